// Round 2
// baseline (10.443 us; speedup 1.0000x reference)
//
#include <hip/hip_runtime.h>
#include <math.h>

// Live computation (rest of the reference is dead code — see R0 notes):
//   x4[j] = x[2j]*w00 + x[2j+1]*w01 + x[28+2j]*w10 + x[28+2j+1]*w11 + b0, j<4
//   k[p]  = |prod_j cos((x4[j]-proto[p,j])*0.5)|, p<20
//   logits[c] = sum_p k[p]*cls_w[c,p] + cls_b[c], c<10
//   out = log_softmax(logits)  (10 floats)
//
// Single wave, no LDS, no barriers. All global loads issued up front so the
// HBM latencies overlap (one cold-load latency instead of two serialized).
// Cross-lane movement via __shfl (64-lane wave).

__global__ void __launch_bounds__(64)
HybridQuanvolution_kernel(const float* __restrict__ x,
                          const float* __restrict__ conv_w,
                          const float* __restrict__ conv_b,
                          const float* __restrict__ prototypes,
                          const float* __restrict__ cls_w,
                          const float* __restrict__ cls_b,
                          float* __restrict__ out) {
    const int t = threadIdx.x;

    // ---- issue every load immediately (independent; latencies overlap) ----
    const float4 cwv = *reinterpret_cast<const float4*>(conv_w);   // w00 w01 w10 w11
    const float  b0  = conv_b[0];
    const float4 xa = *reinterpret_cast<const float4*>(x);         // x[0..3]
    const float4 xb = *reinterpret_cast<const float4*>(x + 4);     // x[4..7]
    const float4 xc = *reinterpret_cast<const float4*>(x + 28);    // x[28..31]
    const float4 xd = *reinterpret_cast<const float4*>(x + 32);    // x[32..35]

    float4 pv = make_float4(0.f, 0.f, 0.f, 0.f);
    if (t < 20)  // prototypes[t, 0..3]; t*784*4B is 16B-aligned
        pv = *reinterpret_cast<const float4*>(prototypes + t * 784);

    float wv[20];
    #pragma unroll
    for (int i = 0; i < 20; ++i) wv[i] = 0.f;
    float bv = 0.f;
    if (t < 10) {  // cls_w[t, 0..19]; t*20*4B = 80t bytes, 16B-aligned
        #pragma unroll
        for (int i = 0; i < 5; ++i)
            reinterpret_cast<float4*>(wv)[i] =
                reinterpret_cast<const float4*>(cls_w + t * 20)[i];
        bv = cls_b[t];
    }

    // ---- k[t] for t<20 ----
    const float r0[8] = {xa.x, xa.y, xa.z, xa.w, xb.x, xb.y, xb.z, xb.w};
    const float r1[8] = {xc.x, xc.y, xc.z, xc.w, xd.x, xd.y, xd.z, xd.w};
    const float pj[4] = {pv.x, pv.y, pv.z, pv.w};
    float k = 0.f;
    if (t < 20) {
        float prod = 1.f;
        #pragma unroll
        for (int j = 0; j < 4; ++j) {
            const float x4 = r0[2 * j] * cwv.x + r0[2 * j + 1] * cwv.y +
                             r1[2 * j] * cwv.z + r1[2 * j + 1] * cwv.w + b0;
            prod *= cosf((x4 - pj[j]) * 0.5f);
        }
        k = fabsf(prod);
    }

    // ---- logits: broadcast k[0..19] via shuffles (all 64 lanes participate) ----
    float acc = bv;
    #pragma unroll
    for (int p = 0; p < 20; ++p) acc += __shfl(k, p) * wv[p];

    // ---- 10-wide log-softmax via shuffles ----
    float lg[10];
    #pragma unroll
    for (int c = 0; c < 10; ++c) lg[c] = __shfl(acc, c);
    float m = -INFINITY;
    #pragma unroll
    for (int c = 0; c < 10; ++c) m = fmaxf(m, lg[c]);
    float s = 0.f;
    #pragma unroll
    for (int c = 0; c < 10; ++c) s += expf(lg[c] - m);

    if (t < 10) out[t] = acc - m - logf(s);
}

extern "C" void kernel_launch(void* const* d_in, const int* in_sizes, int n_in,
                              void* d_out, int out_size, void* d_ws, size_t ws_size,
                              hipStream_t stream) {
    const float* x          = (const float*)d_in[0];
    const float* conv_w     = (const float*)d_in[1];
    const float* conv_b     = (const float*)d_in[2];
    const float* prototypes = (const float*)d_in[3];
    const float* cls_w      = (const float*)d_in[4];
    const float* cls_b      = (const float*)d_in[5];
    float* out = (float*)d_out;

    HybridQuanvolution_kernel<<<1, 64, 0, stream>>>(x, conv_w, conv_b, prototypes,
                                                    cls_w, cls_b, out);
}

// Round 3
// 10.050 us; speedup vs baseline: 1.0391x; 1.0391x over previous
//
#include <hip/hip_runtime.h>
#include <math.h>

// Live computation (rest of the reference is dead code — see R0 notes):
//   x4[j] = x[2j]*w00 + x[2j+1]*w01 + x[28+2j]*w10 + x[28+2j+1]*w11 + b0, j<4
//   k[p]  = |prod_j cos((x4[j]-proto[p,j])*0.5)|, p<20
//   logits[c] = sum_p k[p]*cls_w[c,p] + cls_b[c], c<10
//   out = log_softmax(logits)  (10 floats)
//
// Single wave. All global loads issued up front (latencies overlap under one
// cold-HBM round trip). k broadcast via LDS + ONE barrier (measured faster
// than a 20-deep bpermute chain in R2); 10-wide softmax via shuffles (no
// second barrier).

__global__ void __launch_bounds__(64)
HybridQuanvolution_kernel(const float* __restrict__ x,
                          const float* __restrict__ conv_w,
                          const float* __restrict__ conv_b,
                          const float* __restrict__ prototypes,
                          const float* __restrict__ cls_w,
                          const float* __restrict__ cls_b,
                          float* __restrict__ out) {
    __shared__ float k_sh[20];
    const int t = threadIdx.x;

    // ---- issue every load immediately (independent; latencies overlap) ----
    const float4 cwv = *reinterpret_cast<const float4*>(conv_w);   // w00 w01 w10 w11
    const float  b0  = conv_b[0];
    const float4 xa = *reinterpret_cast<const float4*>(x);         // x[0..3]
    const float4 xb = *reinterpret_cast<const float4*>(x + 4);     // x[4..7]
    const float4 xc = *reinterpret_cast<const float4*>(x + 28);    // x[28..31]
    const float4 xd = *reinterpret_cast<const float4*>(x + 32);    // x[32..35]

    float4 pv = make_float4(0.f, 0.f, 0.f, 0.f);
    if (t < 20)  // prototypes[t, 0..3]; t*784*4B is 16B-aligned
        pv = *reinterpret_cast<const float4*>(prototypes + t * 784);

    float wv[20];
    float bv = 0.f;
    if (t < 10) {  // cls_w[t, 0..19]; 80t bytes, 16B-aligned — issued pre-barrier
        #pragma unroll
        for (int i = 0; i < 5; ++i)
            reinterpret_cast<float4*>(wv)[i] =
                reinterpret_cast<const float4*>(cls_w + t * 20)[i];
        bv = cls_b[t];
    } else {
        #pragma unroll
        for (int i = 0; i < 20; ++i) wv[i] = 0.f;
    }

    // ---- k[t] for t<20, broadcast through LDS ----
    if (t < 20) {
        const float r0[8] = {xa.x, xa.y, xa.z, xa.w, xb.x, xb.y, xb.z, xb.w};
        const float r1[8] = {xc.x, xc.y, xc.z, xc.w, xd.x, xd.y, xd.z, xd.w};
        const float pj[4] = {pv.x, pv.y, pv.z, pv.w};
        float prod = 1.f;
        #pragma unroll
        for (int j = 0; j < 4; ++j) {
            const float x4 = r0[2 * j] * cwv.x + r0[2 * j + 1] * cwv.y +
                             r1[2 * j] * cwv.z + r1[2 * j + 1] * cwv.w + b0;
            prod *= cosf((x4 - pj[j]) * 0.5f);
        }
        k_sh[t] = fabsf(prod);
    }
    __syncthreads();

    // ---- logits (lanes 0..9; k_sh reads broadcast, conflict-free) ----
    float acc = bv;
    #pragma unroll
    for (int p = 0; p < 20; ++p) acc += k_sh[p] * wv[p];

    // ---- 10-wide log-softmax via shuffles (no second barrier) ----
    float lg[10];
    #pragma unroll
    for (int c = 0; c < 10; ++c) lg[c] = __shfl(acc, c);
    float m = -INFINITY;
    #pragma unroll
    for (int c = 0; c < 10; ++c) m = fmaxf(m, lg[c]);
    float s = 0.f;
    #pragma unroll
    for (int c = 0; c < 10; ++c) s += expf(lg[c] - m);

    if (t < 10) out[t] = acc - m - logf(s);
}

extern "C" void kernel_launch(void* const* d_in, const int* in_sizes, int n_in,
                              void* d_out, int out_size, void* d_ws, size_t ws_size,
                              hipStream_t stream) {
    const float* x          = (const float*)d_in[0];
    const float* conv_w     = (const float*)d_in[1];
    const float* conv_b     = (const float*)d_in[2];
    const float* prototypes = (const float*)d_in[3];
    const float* cls_w      = (const float*)d_in[4];
    const float* cls_b      = (const float*)d_in[5];
    float* out = (float*)d_out;

    HybridQuanvolution_kernel<<<1, 64, 0, stream>>>(x, conv_w, conv_b, prototypes,
                                                    cls_w, cls_b, out);
}